// Round 17
// baseline (370.280 us; speedup 1.0000x reference)
//
#include <hip/hip_runtime.h>
#include <math.h>

#define NN 50000
#define NE 800000
#define KIN 256
#define F 192      // HEADS*HID
#define NH 3
#define NC 40
#define CNT4_BLKS ((NE/4 + 255)/256)       // 782
#define CONV_N (KIN*F + F*F + 48*F)        // 95232
#define CONV_BLKS ((CONV_N+255)/256)       // 372
#define GEMM_GRID_C ((NN+63)/64)           // 782
#define EMIT_BLKS 49                       // ceil(NN/1024)

typedef unsigned short u16;
typedef unsigned int   u32;
typedef __attribute__((ext_vector_type(8))) short bf16x8;
typedef __attribute__((ext_vector_type(4))) float f32x4;

static __device__ __forceinline__ u16 f2bf(float f){
  u32 u = __float_as_uint(f);
  u32 r = (u + 0x7fffu + ((u >> 16) & 1u)) >> 16;   // RNE
  return (u16)r;
}

// ---------------- CSR count (4 edges/thread) + weight converts, one launch ------
__global__ void count_conv_kernel(const int* __restrict__ dst, int* __restrict__ cnt,
                                  const float* __restrict__ W1, const float* __restrict__ W2,
                                  const float* __restrict__ Wout,
                                  u16* __restrict__ w1t, u16* __restrict__ w2t, u16* __restrict__ wot){
  int b = blockIdx.x;
  if (b < CNT4_BLKS){
    int e = (b*256 + threadIdx.x)*4;
    if (e + 3 < NE){
      int4 d4 = *(const int4*)&dst[e];
      atomicAdd(&cnt[d4.x], 1);
      atomicAdd(&cnt[d4.y], 1);
      atomicAdd(&cnt[d4.z], 1);
      atomicAdd(&cnt[d4.w], 1);
    } else if (e < NE){
      for (int i=e; i<NE; i++) atomicAdd(&cnt[dst[i]], 1);
    }
    return;
  }
  int e = (b - CNT4_BLKS)*256 + threadIdx.x;
  if (e < KIN*F){
    int c = e / KIN, r = e % KIN;
    w1t[e] = f2bf(W1[(size_t)r*F + c]);       // W1^T [n][k]
    return;
  }
  int e2 = e - KIN*F;
  if (e2 < F*F){
    int c = e2 / F, r = e2 % F;
    w2t[e2] = f2bf(W2[(size_t)r*F + c]);      // W2^T [n][k]
    return;
  }
  int e3 = e2 - F*F;
  if (e3 < 48*F){
    int n = e3 / F, k = e3 % F;
    wot[e3] = (n < NC)? f2bf(Wout[(size_t)k*NC + n]) : (u16)0;
  }
}

// ---------------- fused partial+scan+emit ----------------
__global__ __launch_bounds__(256) void emit_all(int* __restrict__ cnt, int* __restrict__ row_ptr){
  __shared__ int ts[256];
  __shared__ int s_pred;
  const int b = blockIdx.x, t = threadIdx.x;
  const int lim = b*1024;
  int pred = 0;
  for (int i = t*4; i < lim; i += 1024){
    int4 v = *(const int4*)&cnt[i];
    pred += v.x + v.y + v.z + v.w;
  }
  ts[t] = pred;
  __syncthreads();
  for (int off=128; off; off>>=1){
    if (t < off) ts[t] += ts[t+off];
    __syncthreads();
  }
  if (t == 0) s_pred = ts[0];
  __syncthreads();
  const int base = lim + t*4;
  int4 v = make_int4(0,0,0,0);
  if (base + 3 < NN) v = *(const int4*)&cnt[base];
  else if (base < NN){
    v.x = cnt[base];
    if (base+1 < NN) v.y = cnt[base+1];
    if (base+2 < NN) v.z = cnt[base+2];
  }
  int tot = v.x + v.y + v.z + v.w;
  ts[t] = tot;
  __syncthreads();
  #pragma unroll
  for (int off=1; off<256; off<<=1){
    int val = (t >= off)? ts[t-off] : 0;
    __syncthreads();
    ts[t] += val;
    __syncthreads();
  }
  int off0 = s_pred + ts[t] - tot;
  if (base + 3 < NN){
    row_ptr[base]   = off0;
    row_ptr[base+1] = off0 + v.x;
    row_ptr[base+2] = off0 + v.x + v.y;
    row_ptr[base+3] = off0 + v.x + v.y + v.z;
    *(int4*)&cnt[base] = make_int4(0,0,0,0);
  } else if (base < NN){
    row_ptr[base] = off0; cnt[base] = 0;
    if (base+1 < NN){ row_ptr[base+1] = off0 + v.x; cnt[base+1] = 0; }
    if (base+2 < NN){ row_ptr[base+2] = off0 + v.x + v.y; cnt[base+2] = 0; }
  }
  if (b == 0 && t == 0) row_ptr[NN] = NE;
}

// ---------------- MFMA GEMM, SW-pipelined K-loop ----------------
// A[NN x K] @ Bt[192 x K](bf16) -> C[NN x 192](bf16), + fused attention dots.
// Pipeline: tile regs -> LDS -> barrier -> ISSUE NEXT TILE LOADS -> ds_read+MFMA.
// Outstanding loads drain at next iter's reg-use (after MFMA covers latency).
#define SAK 72   // u16 stride; dword stride 36 -> all ds ops <=2-way bank alias (free)
#define SC  196  // u16 stride for C-stage
template<int K, bool CONVA, bool FILL>
__global__ __launch_bounds__(256) void gemm_mfma(const void* __restrict__ Araw, const u16* __restrict__ Bt,
                                                 u16* __restrict__ C,
                                                 const float* __restrict__ att_src, const float* __restrict__ att_dst,
                                                 float* __restrict__ a_src4, float* __restrict__ a_dst4,
                                                 const int* __restrict__ fsrc, const int* __restrict__ fdst,
                                                 const int* __restrict__ row_ptr, int* __restrict__ cur,
                                                 int* __restrict__ col){
  if (FILL && blockIdx.x >= GEMM_GRID_C){
    int e = ((blockIdx.x - GEMM_GRID_C)*256 + threadIdx.x)*4;
    if (e + 3 < NE){
      int4 d4 = *(const int4*)&fdst[e];
      int4 s4 = *(const int4*)&fsrc[e];
      int p0 = row_ptr[d4.x] + atomicAdd(&cur[d4.x], 1);
      int p1 = row_ptr[d4.y] + atomicAdd(&cur[d4.y], 1);
      int p2 = row_ptr[d4.z] + atomicAdd(&cur[d4.z], 1);
      int p3 = row_ptr[d4.w] + atomicAdd(&cur[d4.w], 1);
      col[p0] = s4.x; col[p1] = s4.y; col[p2] = s4.z; col[p3] = s4.w;
    } else if (e < NE){
      for (int i=e; i<NE; i++){
        int d = fdst[i];
        int p = row_ptr[d] + atomicAdd(&cur[d], 1);
        col[p] = fsrc[i];
      }
    }
    return;
  }
  __shared__ __align__(16) union {
    struct { u16 As[64*SAK]; u16 Bs[192*SAK]; } st;
    u16 Cs[64*SC];
  } sh;
  const int t = threadIdx.x;
  const int wave = t >> 6, lane = t & 63;
  const int quad = lane >> 4, l16 = lane & 15;
  const int r0 = blockIdx.x*64;

  f32x4 acc[4][3];
  #pragma unroll
  for (int rt=0;rt<4;rt++)
    #pragma unroll
    for (int ct=0;ct<3;ct++) acc[rt][ct] = (f32x4){0.f,0.f,0.f,0.f};

  const int arow = t >> 2, akq = (t & 3)*16;
  const bool okA = (r0 + arow) < NN;
  float4 fa[4];                 // CONVA prefetch regs
  uint4  ua[2];                 // bf16 prefetch regs
  uint4  ub[6];                 // B prefetch regs

  auto loadA = [&](int k0){
    if (CONVA){
      const float* Af = (const float*)Araw;
      if (okA){
        const float* p = &Af[(size_t)(r0+arow)*K + k0 + akq];
        fa[0] = *(const float4*)(p+0);
        fa[1] = *(const float4*)(p+4);
        fa[2] = *(const float4*)(p+8);
        fa[3] = *(const float4*)(p+12);
      } else {
        fa[0] = fa[1] = fa[2] = fa[3] = make_float4(0,0,0,0);
      }
    } else {
      const u16* Ab = (const u16*)Araw;
      if (okA){
        ua[0] = *(const uint4*)&Ab[(size_t)(r0+arow)*K + k0 + akq];
        ua[1] = *(const uint4*)&Ab[(size_t)(r0+arow)*K + k0 + akq + 8];
      } else {
        ua[0] = ua[1] = make_uint4(0,0,0,0);
      }
    }
  };
  auto loadB = [&](int k0){
    #pragma unroll
    for (int i=0;i<6;i++){
      int idx = t + i*256;
      int n = idx >> 3, kc = idx & 7;
      ub[i] = *(const uint4*)&Bt[(size_t)n*K + k0 + kc*8];
    }
  };
  auto storeAB = [&](){
    if (CONVA){
      uint4 pa, pb;
      pa.x = (u32)f2bf(fa[0].x) | ((u32)f2bf(fa[0].y) << 16);
      pa.y = (u32)f2bf(fa[0].z) | ((u32)f2bf(fa[0].w) << 16);
      pa.z = (u32)f2bf(fa[1].x) | ((u32)f2bf(fa[1].y) << 16);
      pa.w = (u32)f2bf(fa[1].z) | ((u32)f2bf(fa[1].w) << 16);
      pb.x = (u32)f2bf(fa[2].x) | ((u32)f2bf(fa[2].y) << 16);
      pb.y = (u32)f2bf(fa[2].z) | ((u32)f2bf(fa[2].w) << 16);
      pb.z = (u32)f2bf(fa[3].x) | ((u32)f2bf(fa[3].y) << 16);
      pb.w = (u32)f2bf(fa[3].z) | ((u32)f2bf(fa[3].w) << 16);
      *(uint4*)&sh.st.As[arow*SAK + akq]     = pa;
      *(uint4*)&sh.st.As[arow*SAK + akq + 8] = pb;
    } else {
      *(uint4*)&sh.st.As[arow*SAK + akq]     = ua[0];
      *(uint4*)&sh.st.As[arow*SAK + akq + 8] = ua[1];
    }
    #pragma unroll
    for (int i=0;i<6;i++){
      int idx = t + i*256;
      int n = idx >> 3, kc = idx & 7;
      *(uint4*)&sh.st.Bs[n*SAK + kc*8] = ub[i];
    }
  };

  loadA(0); loadB(0);
  #pragma unroll
  for (int ks=0; ks<K/64; ks++){
    __syncthreads();            // prior iter's ds_reads done -> LDS reusable
    storeAB();                  // regs -> LDS (waits the prefetch loads here)
    __syncthreads();            // staging visible; no vm ops pending at barrier
    if (ks+1 < K/64){           // issue NEXT tile loads; drain overlaps MFMA
      loadA((ks+1)*64);
      loadB((ks+1)*64);
    }
    bf16x8 af[4][2], bf[3][2];
    #pragma unroll
    for (int kf=0;kf<2;kf++){
      #pragma unroll
      for (int rt=0;rt<4;rt++) af[rt][kf] = *(const bf16x8*)&sh.st.As[(rt*16 + l16)*SAK + kf*32 + quad*8];
      #pragma unroll
      for (int ct=0;ct<3;ct++) bf[ct][kf] = *(const bf16x8*)&sh.st.Bs[(wave*48 + ct*16 + l16)*SAK + kf*32 + quad*8];
    }
    #pragma unroll
    for (int kf=0;kf<2;kf++)
      #pragma unroll
      for (int rt=0;rt<4;rt++)
        #pragma unroll
        for (int ct=0;ct<3;ct++)
          acc[rt][ct] = __builtin_amdgcn_mfma_f32_16x16x32_bf16(af[rt][kf], bf[ct][kf], acc[rt][ct], 0, 0, 0);
  }

  __syncthreads();   // frag reads done -> safe to overwrite union with Cs
  #pragma unroll
  for (int ct=0;ct<3;ct++){
    const int n = wave*48 + ct*16 + l16;
    #pragma unroll
    for (int rt=0;rt<4;rt++){
      #pragma unroll
      for (int reg=0;reg<4;reg++){
        const int m = rt*16 + quad*4 + reg;
        sh.Cs[m*SC + n] = f2bf(acc[rt][ct][reg]);
      }
    }
  }
  __syncthreads();
  {
    int row = t >> 2, c0 = (t & 3)*6;
    int grow = r0 + row;
    if (grow < NN){
      #pragma unroll
      for (int j=0;j<6;j++){
        int ch = c0 + j;
        uint4 v = *(const uint4*)&sh.Cs[row*SC + ch*8];
        *(uint4*)&C[(size_t)grow*F + ch*8] = v;
      }
    }
  }
  if (t < 192){
    int row = t & 63, head = t >> 6;
    int grow = r0 + row;
    if (grow < NN){
      float ps = 0.f, pd = 0.f;
      #pragma unroll
      for (int j=0;j<8;j++){
        uint4 v = *(const uint4*)&sh.Cs[row*SC + head*64 + j*8];
        float4 w0 = *(const float4*)&att_src[head*64 + j*8];
        float4 w1 = *(const float4*)&att_src[head*64 + j*8 + 4];
        float4 d0 = *(const float4*)&att_dst[head*64 + j*8];
        float4 d1 = *(const float4*)&att_dst[head*64 + j*8 + 4];
        float c0f = __uint_as_float(v.x << 16), c1f = __uint_as_float(v.x & 0xffff0000u);
        float c2f = __uint_as_float(v.y << 16), c3f = __uint_as_float(v.y & 0xffff0000u);
        float c4f = __uint_as_float(v.z << 16), c5f = __uint_as_float(v.z & 0xffff0000u);
        float c6f = __uint_as_float(v.w << 16), c7f = __uint_as_float(v.w & 0xffff0000u);
        ps = fmaf(c0f,w0.x,fmaf(c1f,w0.y,fmaf(c2f,w0.z,fmaf(c3f,w0.w,ps))));
        ps = fmaf(c4f,w1.x,fmaf(c5f,w1.y,fmaf(c6f,w1.z,fmaf(c7f,w1.w,ps))));
        pd = fmaf(c0f,d0.x,fmaf(c1f,d0.y,fmaf(c2f,d0.z,fmaf(c3f,d0.w,pd))));
        pd = fmaf(c4f,d1.x,fmaf(c5f,d1.y,fmaf(c6f,d1.z,fmaf(c7f,d1.w,pd))));
      }
      a_src4[(size_t)grow*4 + head] = ps;
      a_dst4[(size_t)grow*4 + head] = pd;
    }
  }
}

// ---------------- GAT aggregation: ONE-PASS, one wave per dst node ----------------
__global__ __launch_bounds__(256) void gat_agg_wave(const u16* __restrict__ hb,
    const float* __restrict__ a_src4, const float* __restrict__ a_dst4,
    const int* __restrict__ row_ptr, const int* __restrict__ col,
    const float* __restrict__ bias, u16* __restrict__ out){
  __shared__ float s_al[4][64][4];
  const int t = threadIdx.x;
  const int lane = t & 63;
  const int w = t >> 6;
  const int d = blockIdx.x*4 + w;
  if (d >= NN) return;
  const int e0  = row_ptr[d];
  const int deg = row_ptr[d+1] - e0;
  const int ecount = deg + 1;                 // implicit self-loop at j==deg
  const float4 ad = *(const float4*)&a_dst4[(size_t)d*4];

  const int cg = (lane < 48)? lane : lane - 48;
  const int hg = (lane < 48)? (lane >> 4) : 0;
  const int cgo = cg*4;
  float4 acc = make_float4(0.f,0.f,0.f,0.f);
  float sl0=0.f, sl1=0.f, sl2=0.f;

  for (int base=0; base<ecount; base+=64){
    int j = base + lane;
    bool valid = j < ecount;
    int sn = d;
    if (j < deg) sn = col[e0+j];
    float4 as = *(const float4*)&a_src4[(size_t)sn*4];
    float l0 = as.x + ad.x; l0 = (l0>0.f)? l0 : 0.2f*l0;
    float l1 = as.y + ad.y; l1 = (l1>0.f)? l1 : 0.2f*l1;
    float l2 = as.z + ad.z; l2 = (l2>0.f)? l2 : 0.2f*l2;
    float E0 = valid? __expf(l0) : 0.f;
    float E1 = valid? __expf(l1) : 0.f;
    float E2 = valid? __expf(l2) : 0.f;
    sl0 += E0; sl1 += E1; sl2 += E2;
    float4 st; st.x = E0; st.y = E1; st.z = E2; st.w = 0.f;
    *(float4*)&s_al[w][lane][0] = st;
    __builtin_amdgcn_wave_barrier();
    int cnt = ecount - base; if (cnt > 64) cnt = 64;
    int jj = 0;
    for (; jj+4 <= cnt; jj += 4){
      int sA = __builtin_amdgcn_readlane(sn, jj);
      int sB = __builtin_amdgcn_readlane(sn, jj+1);
      int sC = __builtin_amdgcn_readlane(sn, jj+2);
      int sD = __builtin_amdgcn_readlane(sn, jj+3);
      uint2 pA = *(const uint2*)(hb + sA*F + cgo);
      uint2 pB = *(const uint2*)(hb + sB*F + cgo);
      uint2 pC = *(const uint2*)(hb + sC*F + cgo);
      uint2 pD = *(const uint2*)(hb + sD*F + cgo);
      float aA = s_al[w][jj  ][hg];
      float aB = s_al[w][jj+1][hg];
      float aC = s_al[w][jj+2][hg];
      float aD = s_al[w][jj+3][hg];
      acc.x = fmaf(aA, __uint_as_float(pA.x << 16),         acc.x);
      acc.y = fmaf(aA, __uint_as_float(pA.x & 0xffff0000u), acc.y);
      acc.z = fmaf(aA, __uint_as_float(pA.y << 16),         acc.z);
      acc.w = fmaf(aA, __uint_as_float(pA.y & 0xffff0000u), acc.w);
      acc.x = fmaf(aB, __uint_as_float(pB.x << 16),         acc.x);
      acc.y = fmaf(aB, __uint_as_float(pB.x & 0xffff0000u), acc.y);
      acc.z = fmaf(aB, __uint_as_float(pB.y << 16),         acc.z);
      acc.w = fmaf(aB, __uint_as_float(pB.y & 0xffff0000u), acc.w);
      acc.x = fmaf(aC, __uint_as_float(pC.x << 16),         acc.x);
      acc.y = fmaf(aC, __uint_as_float(pC.x & 0xffff0000u), acc.y);
      acc.z = fmaf(aC, __uint_as_float(pC.y << 16),         acc.z);
      acc.w = fmaf(aC, __uint_as_float(pC.y & 0xffff0000u), acc.w);
      acc.x = fmaf(aD, __uint_as_float(pD.x << 16),         acc.x);
      acc.y = fmaf(aD, __uint_as_float(pD.x & 0xffff0000u), acc.y);
      acc.z = fmaf(aD, __uint_as_float(pD.y << 16),         acc.z);
      acc.w = fmaf(aD, __uint_as_float(pD.y & 0xffff0000u), acc.w);
    }
    for (; jj < cnt; jj++){
      int sA = __builtin_amdgcn_readlane(sn, jj);
      uint2 pA = *(const uint2*)(hb + sA*F + cgo);
      float aA = s_al[w][jj][hg];
      acc.x = fmaf(aA, __uint_as_float(pA.x << 16),         acc.x);
      acc.y = fmaf(aA, __uint_as_float(pA.x & 0xffff0000u), acc.y);
      acc.z = fmaf(aA, __uint_as_float(pA.y << 16),         acc.z);
      acc.w = fmaf(aA, __uint_as_float(pA.y & 0xffff0000u), acc.w);
    }
    __builtin_amdgcn_wave_barrier();
  }
  #pragma unroll
  for (int off=32; off; off>>=1){
    sl0 += __shfl_xor(sl0, off);
    sl1 += __shfl_xor(sl1, off);
    sl2 += __shfl_xor(sl2, off);
  }
  if (lane < 48){
    float inv = 1.f / ((hg==0)? sl0 : ((hg==1)? sl1 : sl2));
    float4 b4 = *(const float4*)&bias[cg*4];
    uint2 o;
    o.x = (u32)f2bf(fmaxf(fmaf(acc.x, inv, b4.x), 0.f))
        | ((u32)f2bf(fmaxf(fmaf(acc.y, inv, b4.y), 0.f)) << 16);
    o.y = (u32)f2bf(fmaxf(fmaf(acc.z, inv, b4.z), 0.f))
        | ((u32)f2bf(fmaxf(fmaf(acc.w, inv, b4.w), 0.f)) << 16);
    *(uint2*)&out[(size_t)d*F + cg*4] = o;
  }
}

// ---------------- output GEMM via MFMA, no LDS ----------------
__global__ __launch_bounds__(256) void gemm_out_mfma(const u16* __restrict__ A,
    const u16* __restrict__ Wt, const float* __restrict__ bias, float* __restrict__ out){
  const int t = threadIdx.x;
  const int wave = t >> 6, lane = t & 63;
  const int quad = lane >> 4, l16 = lane & 15;
  const int rbase = blockIdx.x*64 + wave*16;
  const int arow = rbase + l16;
  f32x4 acc[3];
  #pragma unroll
  for (int ct=0;ct<3;ct++) acc[ct] = (f32x4){0.f,0.f,0.f,0.f};
  #pragma unroll
  for (int ks=0; ks<6; ks++){
    const int k0 = ks*32;
    union { uint4 u; bf16x8 h; } cva;
    cva.u = make_uint4(0,0,0,0);
    if (arow < NN) cva.u = *(const uint4*)&A[(size_t)arow*F + k0 + quad*8];
    #pragma unroll
    for (int ct=0;ct<3;ct++){
      bf16x8 bfr = *(const bf16x8*)&Wt[(size_t)(ct*16 + l16)*F + k0 + quad*8];
      acc[ct] = __builtin_amdgcn_mfma_f32_16x16x32_bf16(cva.h, bfr, acc[ct], 0, 0, 0);
    }
  }
  #pragma unroll
  for (int ct=0;ct<3;ct++){
    const int n = ct*16 + l16;
    #pragma unroll
    for (int reg=0;reg<4;reg++){
      const int m = quad*4 + reg;
      const int grow = rbase + m;
      if (grow < NN && n < NC) out[(size_t)grow*NC + n] = acc[ct][reg] + bias[n];
    }
  }
}

extern "C" void kernel_launch(void* const* d_in, const int* in_sizes, int n_in,
                              void* d_out, int out_size, void* d_ws, size_t ws_size,
                              hipStream_t stream){
  const float* x    = (const float*)d_in[0];
  const int*   ei   = (const int*)  d_in[1];
  const float* W1   = (const float*)d_in[2];
  const float* as1  = (const float*)d_in[3];
  const float* ad1  = (const float*)d_in[4];
  const float* b1   = (const float*)d_in[5];
  const float* W2   = (const float*)d_in[6];
  const float* as2  = (const float*)d_in[7];
  const float* ad2  = (const float*)d_in[8];
  const float* b2   = (const float*)d_in[9];
  const float* Wout = (const float*)d_in[10];
  const float* bout = (const float*)d_in[11];
  float* out = (float*)d_out;

  // workspace carve-out
  u16* w1t = (u16*)d_ws;                          // KIN*F  (W1^T bf16)
  u16* w2t = w1t + (size_t)KIN*F;                 // F*F    (W2^T bf16)
  u16* wot = w2t + (size_t)F*F;                   // 48*F   (Wout^T bf16, padded)
  u16* hb1 = wot + (size_t)48*F;                  // NN*F
  u16* hb2 = hb1 + (size_t)NN*F;                  // NN*F
  u16* gb1 = hb2 + (size_t)NN*F;                  // NN*F
  u16* gb2 = gb1 + (size_t)NN*F;                  // NN*F
  float* a_src4 = (float*)(gb2 + (size_t)NN*F);   // NN*4
  float* a_dst4 = a_src4 + (size_t)NN*4;          // NN*4
  int* row_ptr  = (int*)(a_dst4 + (size_t)NN*4);  // NN+1
  int* col      = row_ptr + (NN+1);               // NE
  int* cnt      = col + NE;                       // NN

  const int* srcv = ei;
  const int* dstv = ei + NE;

  // CSR build: memset -> count(x4)+conv -> emit_all -> fill(x4, piggybacked on gemm1)
  hipMemsetAsync(cnt, 0, NN*sizeof(int), stream);
  count_conv_kernel<<<CNT4_BLKS + CONV_BLKS, 256, 0, stream>>>(dstv, cnt, W1, W2, Wout, w1t, w2t, wot);
  emit_all<<<EMIT_BLKS, 256, 0, stream>>>(cnt, row_ptr);

  const int AGG_GRID = (NN + 3)/4;
  // layer 1: pipelined GEMM (x converted inline) + piggybacked CSR fill blocks
  gemm_mfma<KIN,true,true><<<GEMM_GRID_C + CNT4_BLKS, 256, 0, stream>>>(
      x, w1t, hb1, as1, ad1, a_src4, a_dst4, srcv, dstv, row_ptr, cnt, col);
  gat_agg_wave<<<AGG_GRID, 256, 0, stream>>>(hb1, a_src4, a_dst4, row_ptr, col, b1, gb1);
  // layer 2
  gemm_mfma<F,false,false><<<GEMM_GRID_C, 256, 0, stream>>>(
      gb1, w2t, hb2, as2, ad2, a_src4, a_dst4, nullptr, nullptr, nullptr, nullptr, nullptr);
  gat_agg_wave<<<AGG_GRID, 256, 0, stream>>>(hb2, a_src4, a_dst4, row_ptr, col, b2, gb2);
  // readout
  gemm_out_mfma<<<GEMM_GRID_C, 256, 0, stream>>>(gb2, wot, bout, out);
}

// Round 18
// 335.168 us; speedup vs baseline: 1.1048x; 1.1048x over previous
//
#include <hip/hip_runtime.h>
#include <math.h>

#define NN 50000
#define NE 800000
#define KIN 256
#define F 192      // HEADS*HID
#define NH 3
#define NC 40
#define CNT_BLKS ((NE+255)/256)            // 3125
#define CONV_N (KIN*F + F*F + 48*F)        // 95232
#define CONV_BLKS ((CONV_N+255)/256)       // 372
#define GEMM_GRID_C ((NN+63)/64)           // 782
#define EMIT_BLKS 49                       // ceil(NN/1024)

typedef unsigned short u16;
typedef unsigned int   u32;
typedef __attribute__((ext_vector_type(8))) short bf16x8;
typedef __attribute__((ext_vector_type(4))) float f32x4;

static __device__ __forceinline__ u16 f2bf(float f){
  u32 u = __float_as_uint(f);
  u32 r = (u + 0x7fffu + ((u >> 16) & 1u)) >> 16;   // RNE
  return (u16)r;
}

// ---------------- CSR count + (independent) weight converts, one launch ----------
// R12 lesson: no in-kernel agent fences. R16 lesson: x4 atomics neutral (line-bound).
// R17 lesson: register prefetch across MFMA spills -> scratch traffic; keep simple.
__global__ void count_conv_kernel(const int* __restrict__ dst, int* __restrict__ cnt,
                                  const float* __restrict__ W1, const float* __restrict__ W2,
                                  const float* __restrict__ Wout,
                                  u16* __restrict__ w1t, u16* __restrict__ w2t, u16* __restrict__ wot){
  int b = blockIdx.x;
  if (b < CNT_BLKS){
    int e = b*256 + threadIdx.x;
    if (e < NE) atomicAdd(&cnt[dst[e]], 1);
    return;
  }
  int e = (b - CNT_BLKS)*256 + threadIdx.x;
  if (e < KIN*F){
    int c = e / KIN, r = e % KIN;
    w1t[e] = f2bf(W1[(size_t)r*F + c]);       // W1^T [n][k]
    return;
  }
  int e2 = e - KIN*F;
  if (e2 < F*F){
    int c = e2 / F, r = e2 % F;
    w2t[e2] = f2bf(W2[(size_t)r*F + c]);      // W2^T [n][k]
    return;
  }
  int e3 = e2 - F*F;
  if (e3 < 48*F){
    int n = e3 / F, k = e3 % F;
    wot[e3] = (n < NC)? f2bf(Wout[(size_t)k*NC + n]) : (u16)0;
  }
}

// ---------------- fused partial+scan+emit ----------------
__global__ __launch_bounds__(256) void emit_all(int* __restrict__ cnt, int* __restrict__ row_ptr){
  __shared__ int ts[256];
  __shared__ int s_pred;
  const int b = blockIdx.x, t = threadIdx.x;
  const int lim = b*1024;
  int pred = 0;
  for (int i = t*4; i < lim; i += 1024){
    int4 v = *(const int4*)&cnt[i];
    pred += v.x + v.y + v.z + v.w;
  }
  ts[t] = pred;
  __syncthreads();
  for (int off=128; off; off>>=1){
    if (t < off) ts[t] += ts[t+off];
    __syncthreads();
  }
  if (t == 0) s_pred = ts[0];
  __syncthreads();
  const int base = lim + t*4;
  int4 v = make_int4(0,0,0,0);
  if (base + 3 < NN) v = *(const int4*)&cnt[base];
  else if (base < NN){
    v.x = cnt[base];
    if (base+1 < NN) v.y = cnt[base+1];
    if (base+2 < NN) v.z = cnt[base+2];
  }
  int tot = v.x + v.y + v.z + v.w;
  ts[t] = tot;
  __syncthreads();
  #pragma unroll
  for (int off=1; off<256; off<<=1){
    int val = (t >= off)? ts[t-off] : 0;
    __syncthreads();
    ts[t] += val;
    __syncthreads();
  }
  int off0 = s_pred + ts[t] - tot;
  if (base + 3 < NN){
    row_ptr[base]   = off0;
    row_ptr[base+1] = off0 + v.x;
    row_ptr[base+2] = off0 + v.x + v.y;
    row_ptr[base+3] = off0 + v.x + v.y + v.z;
    *(int4*)&cnt[base] = make_int4(0,0,0,0);
  } else if (base < NN){
    row_ptr[base] = off0; cnt[base] = 0;
    if (base+1 < NN){ row_ptr[base+1] = off0 + v.x; cnt[base+1] = 0; }
    if (base+2 < NN){ row_ptr[base+2] = off0 + v.x + v.y; cnt[base+2] = 0; }
  }
  if (b == 0 && t == 0) row_ptr[NN] = NE;
}

// ---------------- MFMA GEMM: A[NN x K] @ Bt[192 x K](bf16) -> C[NN x 192](bf16)
// + fused attention dots. CONVA: A fp32 converted during staging. FILL: blocks
// beyond GEMM_GRID_C do the CSR fill (independent work, overlaps with MFMA).
#define SAK 72   // u16 stride; dword stride 36 -> all ds ops <=2-way bank alias (free)
#define SC  196  // u16 stride for C-stage
template<int K, bool CONVA, bool FILL>
__global__ __launch_bounds__(256) void gemm_mfma(const void* __restrict__ Araw, const u16* __restrict__ Bt,
                                                 u16* __restrict__ C,
                                                 const float* __restrict__ att_src, const float* __restrict__ att_dst,
                                                 float* __restrict__ a_src4, float* __restrict__ a_dst4,
                                                 const int* __restrict__ fsrc, const int* __restrict__ fdst,
                                                 const int* __restrict__ row_ptr, int* __restrict__ cur,
                                                 int* __restrict__ col){
  if (FILL && blockIdx.x >= GEMM_GRID_C){
    int e = (blockIdx.x - GEMM_GRID_C)*256 + threadIdx.x;
    if (e < NE){
      int d = fdst[e];
      int p = row_ptr[d] + atomicAdd(&cur[d], 1);
      col[p] = fsrc[e];
    }
    return;
  }
  __shared__ __align__(16) union {
    struct { u16 As[64*SAK]; u16 Bs[192*SAK]; } st;
    u16 Cs[64*SC];
  } sh;
  const int t = threadIdx.x;
  const int wave = t >> 6, lane = t & 63;
  const int quad = lane >> 4, l16 = lane & 15;
  const int r0 = blockIdx.x*64;

  f32x4 acc[4][3];
  #pragma unroll
  for (int rt=0;rt<4;rt++)
    #pragma unroll
    for (int ct=0;ct<3;ct++) acc[rt][ct] = (f32x4){0.f,0.f,0.f,0.f};

  for (int k0=0; k0<K; k0+=64){
    __syncthreads();
    {
      int row = t >> 2, kq = (t & 3)*16;
      bool ok = (r0+row) < NN;
      if (CONVA){
        const float* Af = (const float*)Araw;
        float4 v0 = make_float4(0,0,0,0), v1 = v0, v2 = v0, v3 = v0;
        if (ok){
          const float* p = &Af[(size_t)(r0+row)*K + k0 + kq];
          v0 = *(const float4*)(p+0);
          v1 = *(const float4*)(p+4);
          v2 = *(const float4*)(p+8);
          v3 = *(const float4*)(p+12);
        }
        uint4 pa, pb;
        pa.x = (u32)f2bf(v0.x) | ((u32)f2bf(v0.y) << 16);
        pa.y = (u32)f2bf(v0.z) | ((u32)f2bf(v0.w) << 16);
        pa.z = (u32)f2bf(v1.x) | ((u32)f2bf(v1.y) << 16);
        pa.w = (u32)f2bf(v1.z) | ((u32)f2bf(v1.w) << 16);
        pb.x = (u32)f2bf(v2.x) | ((u32)f2bf(v2.y) << 16);
        pb.y = (u32)f2bf(v2.z) | ((u32)f2bf(v2.w) << 16);
        pb.z = (u32)f2bf(v3.x) | ((u32)f2bf(v3.y) << 16);
        pb.w = (u32)f2bf(v3.z) | ((u32)f2bf(v3.w) << 16);
        *(uint4*)&sh.st.As[row*SAK + kq]     = pa;
        *(uint4*)&sh.st.As[row*SAK + kq + 8] = pb;
      } else {
        const u16* Ab = (const u16*)Araw;
        uint4 va = make_uint4(0,0,0,0), vb = va;
        if (ok){
          va = *(const uint4*)&Ab[(size_t)(r0+row)*K + k0 + kq];
          vb = *(const uint4*)&Ab[(size_t)(r0+row)*K + k0 + kq + 8];
        }
        *(uint4*)&sh.st.As[row*SAK + kq]     = va;
        *(uint4*)&sh.st.As[row*SAK + kq + 8] = vb;
      }
    }
    #pragma unroll
    for (int i=0;i<6;i++){
      int idx = t + i*256;
      int n = idx >> 3, kc = idx & 7;
      *(uint4*)&sh.st.Bs[n*SAK + kc*8] = *(const uint4*)&Bt[(size_t)n*K + k0 + kc*8];
    }
    __syncthreads();
    bf16x8 af[4][2], bf[3][2];
    #pragma unroll
    for (int kf=0;kf<2;kf++){
      #pragma unroll
      for (int rt=0;rt<4;rt++) af[rt][kf] = *(const bf16x8*)&sh.st.As[(rt*16 + l16)*SAK + kf*32 + quad*8];
      #pragma unroll
      for (int ct=0;ct<3;ct++) bf[ct][kf] = *(const bf16x8*)&sh.st.Bs[(wave*48 + ct*16 + l16)*SAK + kf*32 + quad*8];
    }
    #pragma unroll
    for (int kf=0;kf<2;kf++)
      #pragma unroll
      for (int rt=0;rt<4;rt++)
        #pragma unroll
        for (int ct=0;ct<3;ct++)
          acc[rt][ct] = __builtin_amdgcn_mfma_f32_16x16x32_bf16(af[rt][kf], bf[ct][kf], acc[rt][ct], 0, 0, 0);
  }

  __syncthreads();   // frag reads done -> safe to overwrite union with Cs
  #pragma unroll
  for (int ct=0;ct<3;ct++){
    const int n = wave*48 + ct*16 + l16;
    #pragma unroll
    for (int rt=0;rt<4;rt++){
      #pragma unroll
      for (int reg=0;reg<4;reg++){
        const int m = rt*16 + quad*4 + reg;
        sh.Cs[m*SC + n] = f2bf(acc[rt][ct][reg]);
      }
    }
  }
  __syncthreads();
  {
    int row = t >> 2, c0 = (t & 3)*6;
    int grow = r0 + row;
    if (grow < NN){
      #pragma unroll
      for (int j=0;j<6;j++){
        int ch = c0 + j;
        uint4 v = *(const uint4*)&sh.Cs[row*SC + ch*8];
        *(uint4*)&C[(size_t)grow*F + ch*8] = v;
      }
    }
  }
  if (t < 192){
    int row = t & 63, head = t >> 6;
    int grow = r0 + row;
    if (grow < NN){
      float ps = 0.f, pd = 0.f;
      #pragma unroll
      for (int j=0;j<8;j++){
        uint4 v = *(const uint4*)&sh.Cs[row*SC + head*64 + j*8];
        float4 w0 = *(const float4*)&att_src[head*64 + j*8];
        float4 w1 = *(const float4*)&att_src[head*64 + j*8 + 4];
        float4 d0 = *(const float4*)&att_dst[head*64 + j*8];
        float4 d1 = *(const float4*)&att_dst[head*64 + j*8 + 4];
        float c0f = __uint_as_float(v.x << 16), c1f = __uint_as_float(v.x & 0xffff0000u);
        float c2f = __uint_as_float(v.y << 16), c3f = __uint_as_float(v.y & 0xffff0000u);
        float c4f = __uint_as_float(v.z << 16), c5f = __uint_as_float(v.z & 0xffff0000u);
        float c6f = __uint_as_float(v.w << 16), c7f = __uint_as_float(v.w & 0xffff0000u);
        ps = fmaf(c0f,w0.x,fmaf(c1f,w0.y,fmaf(c2f,w0.z,fmaf(c3f,w0.w,ps))));
        ps = fmaf(c4f,w1.x,fmaf(c5f,w1.y,fmaf(c6f,w1.z,fmaf(c7f,w1.w,ps))));
        pd = fmaf(c0f,d0.x,fmaf(c1f,d0.y,fmaf(c2f,d0.z,fmaf(c3f,d0.w,pd))));
        pd = fmaf(c4f,d1.x,fmaf(c5f,d1.y,fmaf(c6f,d1.z,fmaf(c7f,d1.w,pd))));
      }
      a_src4[(size_t)grow*4 + head] = ps;
      a_dst4[(size_t)grow*4 + head] = pd;
    }
  }
}

// ---------------- GAT aggregation: ONE-PASS, one wave per dst node ----------------
__global__ __launch_bounds__(256) void gat_agg_wave(const u16* __restrict__ hb,
    const float* __restrict__ a_src4, const float* __restrict__ a_dst4,
    const int* __restrict__ row_ptr, const int* __restrict__ col,
    const float* __restrict__ bias, u16* __restrict__ out){
  __shared__ float s_al[4][64][4];
  const int t = threadIdx.x;
  const int lane = t & 63;
  const int w = t >> 6;
  const int d = blockIdx.x*4 + w;
  if (d >= NN) return;
  const int e0  = row_ptr[d];
  const int deg = row_ptr[d+1] - e0;
  const int ecount = deg + 1;                 // implicit self-loop at j==deg
  const float4 ad = *(const float4*)&a_dst4[(size_t)d*4];

  const int cg = (lane < 48)? lane : lane - 48;
  const int hg = (lane < 48)? (lane >> 4) : 0;
  const int cgo = cg*4;
  float4 acc = make_float4(0.f,0.f,0.f,0.f);
  float sl0=0.f, sl1=0.f, sl2=0.f;

  for (int base=0; base<ecount; base+=64){
    int j = base + lane;
    bool valid = j < ecount;
    int sn = d;
    if (j < deg) sn = col[e0+j];
    float4 as = *(const float4*)&a_src4[(size_t)sn*4];
    float l0 = as.x + ad.x; l0 = (l0>0.f)? l0 : 0.2f*l0;
    float l1 = as.y + ad.y; l1 = (l1>0.f)? l1 : 0.2f*l1;
    float l2 = as.z + ad.z; l2 = (l2>0.f)? l2 : 0.2f*l2;
    float E0 = valid? __expf(l0) : 0.f;
    float E1 = valid? __expf(l1) : 0.f;
    float E2 = valid? __expf(l2) : 0.f;
    sl0 += E0; sl1 += E1; sl2 += E2;
    float4 st; st.x = E0; st.y = E1; st.z = E2; st.w = 0.f;
    *(float4*)&s_al[w][lane][0] = st;
    __builtin_amdgcn_wave_barrier();
    int cnt = ecount - base; if (cnt > 64) cnt = 64;
    int jj = 0;
    for (; jj+4 <= cnt; jj += 4){
      int sA = __builtin_amdgcn_readlane(sn, jj);
      int sB = __builtin_amdgcn_readlane(sn, jj+1);
      int sC = __builtin_amdgcn_readlane(sn, jj+2);
      int sD = __builtin_amdgcn_readlane(sn, jj+3);
      uint2 pA = *(const uint2*)(hb + sA*F + cgo);
      uint2 pB = *(const uint2*)(hb + sB*F + cgo);
      uint2 pC = *(const uint2*)(hb + sC*F + cgo);
      uint2 pD = *(const uint2*)(hb + sD*F + cgo);
      float aA = s_al[w][jj  ][hg];
      float aB = s_al[w][jj+1][hg];
      float aC = s_al[w][jj+2][hg];
      float aD = s_al[w][jj+3][hg];
      acc.x = fmaf(aA, __uint_as_float(pA.x << 16),         acc.x);
      acc.y = fmaf(aA, __uint_as_float(pA.x & 0xffff0000u), acc.y);
      acc.z = fmaf(aA, __uint_as_float(pA.y << 16),         acc.z);
      acc.w = fmaf(aA, __uint_as_float(pA.y & 0xffff0000u), acc.w);
      acc.x = fmaf(aB, __uint_as_float(pB.x << 16),         acc.x);
      acc.y = fmaf(aB, __uint_as_float(pB.x & 0xffff0000u), acc.y);
      acc.z = fmaf(aB, __uint_as_float(pB.y << 16),         acc.z);
      acc.w = fmaf(aB, __uint_as_float(pB.y & 0xffff0000u), acc.w);
      acc.x = fmaf(aC, __uint_as_float(pC.x << 16),         acc.x);
      acc.y = fmaf(aC, __uint_as_float(pC.x & 0xffff0000u), acc.y);
      acc.z = fmaf(aC, __uint_as_float(pC.y << 16),         acc.z);
      acc.w = fmaf(aC, __uint_as_float(pC.y & 0xffff0000u), acc.w);
      acc.x = fmaf(aD, __uint_as_float(pD.x << 16),         acc.x);
      acc.y = fmaf(aD, __uint_as_float(pD.x & 0xffff0000u), acc.y);
      acc.z = fmaf(aD, __uint_as_float(pD.y << 16),         acc.z);
      acc.w = fmaf(aD, __uint_as_float(pD.y & 0xffff0000u), acc.w);
    }
    for (; jj < cnt; jj++){
      int sA = __builtin_amdgcn_readlane(sn, jj);
      uint2 pA = *(const uint2*)(hb + sA*F + cgo);
      float aA = s_al[w][jj][hg];
      acc.x = fmaf(aA, __uint_as_float(pA.x << 16),         acc.x);
      acc.y = fmaf(aA, __uint_as_float(pA.x & 0xffff0000u), acc.y);
      acc.z = fmaf(aA, __uint_as_float(pA.y << 16),         acc.z);
      acc.w = fmaf(aA, __uint_as_float(pA.y & 0xffff0000u), acc.w);
    }
    __builtin_amdgcn_wave_barrier();
  }
  #pragma unroll
  for (int off=32; off; off>>=1){
    sl0 += __shfl_xor(sl0, off);
    sl1 += __shfl_xor(sl1, off);
    sl2 += __shfl_xor(sl2, off);
  }
  if (lane < 48){
    float inv = 1.f / ((hg==0)? sl0 : ((hg==1)? sl1 : sl2));
    float4 b4 = *(const float4*)&bias[cg*4];
    uint2 o;
    o.x = (u32)f2bf(fmaxf(fmaf(acc.x, inv, b4.x), 0.f))
        | ((u32)f2bf(fmaxf(fmaf(acc.y, inv, b4.y), 0.f)) << 16);
    o.y = (u32)f2bf(fmaxf(fmaf(acc.z, inv, b4.z), 0.f))
        | ((u32)f2bf(fmaxf(fmaf(acc.w, inv, b4.w), 0.f)) << 16);
    *(uint2*)&out[(size_t)d*F + cg*4] = o;
  }
}

// ---------------- output GEMM via MFMA, no LDS ----------------
__global__ __launch_bounds__(256) void gemm_out_mfma(const u16* __restrict__ A,
    const u16* __restrict__ Wt, const float* __restrict__ bias, float* __restrict__ out){
  const int t = threadIdx.x;
  const int wave = t >> 6, lane = t & 63;
  const int quad = lane >> 4, l16 = lane & 15;
  const int rbase = blockIdx.x*64 + wave*16;
  const int arow = rbase + l16;
  f32x4 acc[3];
  #pragma unroll
  for (int ct=0;ct<3;ct++) acc[ct] = (f32x4){0.f,0.f,0.f,0.f};
  #pragma unroll
  for (int ks=0; ks<6; ks++){
    const int k0 = ks*32;
    union { uint4 u; bf16x8 h; } cva;
    cva.u = make_uint4(0,0,0,0);
    if (arow < NN) cva.u = *(const uint4*)&A[(size_t)arow*F + k0 + quad*8];
    #pragma unroll
    for (int ct=0;ct<3;ct++){
      bf16x8 bfr = *(const bf16x8*)&Wt[(size_t)(ct*16 + l16)*F + k0 + quad*8];
      acc[ct] = __builtin_amdgcn_mfma_f32_16x16x32_bf16(cva.h, bfr, acc[ct], 0, 0, 0);
    }
  }
  #pragma unroll
  for (int ct=0;ct<3;ct++){
    const int n = ct*16 + l16;
    #pragma unroll
    for (int reg=0;reg<4;reg++){
      const int m = quad*4 + reg;
      const int grow = rbase + m;
      if (grow < NN && n < NC) out[(size_t)grow*NC + n] = acc[ct][reg] + bias[n];
    }
  }
}

extern "C" void kernel_launch(void* const* d_in, const int* in_sizes, int n_in,
                              void* d_out, int out_size, void* d_ws, size_t ws_size,
                              hipStream_t stream){
  const float* x    = (const float*)d_in[0];
  const int*   ei   = (const int*)  d_in[1];
  const float* W1   = (const float*)d_in[2];
  const float* as1  = (const float*)d_in[3];
  const float* ad1  = (const float*)d_in[4];
  const float* b1   = (const float*)d_in[5];
  const float* W2   = (const float*)d_in[6];
  const float* as2  = (const float*)d_in[7];
  const float* ad2  = (const float*)d_in[8];
  const float* b2   = (const float*)d_in[9];
  const float* Wout = (const float*)d_in[10];
  const float* bout = (const float*)d_in[11];
  float* out = (float*)d_out;

  // workspace carve-out
  u16* w1t = (u16*)d_ws;                          // KIN*F  (W1^T bf16)
  u16* w2t = w1t + (size_t)KIN*F;                 // F*F    (W2^T bf16)
  u16* wot = w2t + (size_t)F*F;                   // 48*F   (Wout^T bf16, padded)
  u16* hb1 = wot + (size_t)48*F;                  // NN*F
  u16* hb2 = hb1 + (size_t)NN*F;                  // NN*F
  u16* gb1 = hb2 + (size_t)NN*F;                  // NN*F
  u16* gb2 = gb1 + (size_t)NN*F;                  // NN*F
  float* a_src4 = (float*)(gb2 + (size_t)NN*F);   // NN*4
  float* a_dst4 = a_src4 + (size_t)NN*4;          // NN*4
  int* row_ptr  = (int*)(a_dst4 + (size_t)NN*4);  // NN+1
  int* col      = row_ptr + (NN+1);               // NE
  int* cnt      = col + NE;                       // NN

  const int* srcv = ei;
  const int* dstv = ei + NE;

  // CSR build: memset -> count+conv -> emit_all -> fill (piggybacked on gemm1)
  hipMemsetAsync(cnt, 0, NN*sizeof(int), stream);
  count_conv_kernel<<<CNT_BLKS + CONV_BLKS, 256, 0, stream>>>(dstv, cnt, W1, W2, Wout, w1t, w2t, wot);
  emit_all<<<EMIT_BLKS, 256, 0, stream>>>(cnt, row_ptr);

  const int AGG_GRID = (NN + 3)/4;
  // layer 1: GEMM (x converted inline) + piggybacked CSR fill blocks
  gemm_mfma<KIN,true,true><<<GEMM_GRID_C + CNT_BLKS, 256, 0, stream>>>(
      x, w1t, hb1, as1, ad1, a_src4, a_dst4, srcv, dstv, row_ptr, cnt, col);
  gat_agg_wave<<<AGG_GRID, 256, 0, stream>>>(hb1, a_src4, a_dst4, row_ptr, col, b1, gb1);
  // layer 2
  gemm_mfma<F,false,false><<<GEMM_GRID_C, 256, 0, stream>>>(
      gb1, w2t, hb2, as2, ad2, a_src4, a_dst4, nullptr, nullptr, nullptr, nullptr, nullptr);
  gat_agg_wave<<<AGG_GRID, 256, 0, stream>>>(hb2, a_src4, a_dst4, row_ptr, col, b2, gb2);
  // readout
  gemm_out_mfma<<<GEMM_GRID_C, 256, 0, stream>>>(gb2, wot, bout, out);
}